// Round 2
// baseline (1219.092 us; speedup 1.0000x reference)
//
#include <hip/hip_runtime.h>
#include <math.h>

#define BH 8
#define HH 128
#define WW 128
#define HW 16384

typedef __attribute__((ext_vector_type(8))) short bf16x8;
typedef __attribute__((ext_vector_type(4))) float f32x4;

__device__ inline unsigned short f2bf(float f) {
    union { float f; unsigned u; } v; v.f = f;
    unsigned r = v.u + 0x7FFF + ((v.u >> 16) & 1);
    return (unsigned short)(r >> 16);
}
__device__ inline float bf2f(unsigned short u) {
    union { unsigned u; float f; } v; v.u = (unsigned)u << 16;
    return v.f;
}

// async global->LDS, 16B per lane. LDS dest must be wave-uniform base (+lane*16).
typedef const __attribute__((address_space(1))) void* gptr_t;
typedef __attribute__((address_space(3))) void* lptr_t;
__device__ inline void gload_lds16(const void* g, void* l) {
    __builtin_amdgcn_global_load_lds((gptr_t)g, (lptr_t)l, 16, 0, 0);
}

// ---------------------------------------------------------------------------
// transpose+cast: [B][C][HW] f32 -> [B][HW][C] bf16   (32c x 64pos tiles)
// ---------------------------------------------------------------------------
__global__ __launch_bounds__(256) void transpose_cast(
        const float* __restrict__ in, unsigned short* __restrict__ out, int C) {
    __shared__ float T[32][65];
    int tid = threadIdx.x;
    int pb = blockIdx.x * 64, cb = blockIdx.y * 32, b = blockIdx.z;
    #pragma unroll
    for (int j = 0; j < 8; ++j) {
        int idx = tid + j * 256;
        int c = idx >> 6, p = idx & 63;
        T[c][p] = in[((size_t)(b * C + cb + c)) * HW + pb + p];
    }
    __syncthreads();
    #pragma unroll
    for (int j = 0; j < 8; ++j) {
        int idx = tid + j * 256;
        int p = idx >> 5, c = idx & 31;
        out[((size_t)(b * HW + pb + p)) * C + cb + c] = f2bf(T[c][p]);
    }
}

// ---------------------------------------------------------------------------
// weight repack to bf16 (unchanged)
// ---------------------------------------------------------------------------
__global__ __launch_bounds__(256) void repack_weights(
        const float* __restrict__ w1, const float* __restrict__ w2,
        const float* __restrict__ wih, const float* __restrict__ whh,
        unsigned short* __restrict__ w1t, unsigned short* __restrict__ w2t,
        unsigned short* __restrict__ wg) {
    int i = blockIdx.x * 256 + threadIdx.x;
    if (i < 294912) {
        int t = i >> 15, rem = i & 32767, d = rem >> 8, c = rem & 255;
        w1t[i] = f2bf(w1[((size_t)(d * 256 + c)) * 9 + t]);
    }
    if (i < 294912) {
        int t = i >> 15, co = (i >> 7) & 255, ci = i & 127;
        w2t[i] = f2bf(w2[((size_t)(co * 128 + ci)) * 9 + t]);
    }
    if (i < 196608) {
        int m = i / 384, k = i - m * 384;
        float v = 0.0f;
        if (m < 384) {
            if (k < 128)       v = wih[(size_t)m * 384 + k];
            else if (k < 256)  v = wih[(size_t)m * 384 + 256 + (k - 128)];
            else               v = (m < 256) ? whh[(size_t)m * 128 + (k - 256)] : 0.0f;
        } else {
            v = (k >= 256) ? whh[(size_t)(m - 128) * 128 + (k - 256)] : 0.0f;
        }
        wg[i] = f2bf(v);
    }
}

// ---------------------------------------------------------------------------
// prep_ce (unchanged)
// ---------------------------------------------------------------------------
__global__ __launch_bounds__(256) void prep_ce(
        const float* __restrict__ w2, const float* __restrict__ b2,
        const float* __restrict__ wih,
        float* __restrict__ M, float* __restrict__ cebias) {
    int i = blockIdx.x * 256 + threadIdx.x;
    if (i < 24576) {
        int j = i / 384, m = i - j * 384;
        float acc = 0.0f;
        for (int d = 0; d < 128; ++d)
            acc = fmaf(w2[(size_t)d * 64 + j], wih[(size_t)m * 384 + 128 + d], acc);
        M[i] = acc;
    } else if (i < 24960) {
        int m = i - 24576;
        float acc = 0.0f;
        for (int d = 0; d < 128; ++d)
            acc = fmaf(b2[d], wih[(size_t)m * 384 + 128 + d], acc);
        cebias[m] = acc;
    }
}

// ---------------------------------------------------------------------------
// ce_g (unchanged)
// ---------------------------------------------------------------------------
__global__ __launch_bounds__(384) void ce_g_kernel(
        const float* __restrict__ w1, const float* __restrict__ b1,
        const float* __restrict__ M, const float* __restrict__ cebias,
        float* __restrict__ ce_g) {
    __shared__ float h1[16][64];
    int m = threadIdx.x;
    int pos0 = blockIdx.x * 16;
    for (int e = m; e < 1024; e += 384) {
        int p = e >> 6, j = e & 63;
        int pos = pos0 + p;
        int hh = pos >> 7, wp = pos & 127;
        float xc = -1.0f + 2.0f * (float)wp / 127.0f;
        float yc = -1.0f + 2.0f * (float)hh / 127.0f;
        float a = xc * w1[j*4+0] + yc * w1[j*4+1]
                + xc * 128.0f * w1[j*4+2] + yc * 128.0f * w1[j*4+3] + b1[j];
        h1[p][j] = fmaxf(a, 0.0f);
    }
    __syncthreads();
    float acc[16];
    float cb = cebias[m];
    #pragma unroll
    for (int p = 0; p < 16; ++p) acc[p] = cb;
    for (int j = 0; j < 64; ++j) {
        float Mv = M[(size_t)j * 384 + m];
        #pragma unroll
        for (int p = 0; p < 16; ++p)
            acc[p] = fmaf(h1[p][j], Mv, acc[p]);
    }
    #pragma unroll
    for (int p = 0; p < 16; ++p)
        ce_g[(size_t)(pos0 + p) * 384 + m] = acc[p];
}

// ---------------------------------------------------------------------------
// MFMA conv (3x3 SAME) as 9 shifted GEMMs.
// Round-4: A stays in LDS (gload_lds + quarter-XOR swizzle, double-buffered);
// W moves to per-lane registers (12 x 16B direct global loads per chunk,
// L2-hot, 64B-segment coalesced). LDS 66->16.6 KB, occupancy 2->3 blocks/CU,
// barrier drain shrinks from 8 to 2 async loads/thread.
// ---------------------------------------------------------------------------
template<int CIN, int COUT, bool CONV1>
__global__ __launch_bounds__(256, 3) void conv_mfma(
        const unsigned short* __restrict__ xt,
        const unsigned short* __restrict__ wt,
        const float* __restrict__ bias,
        float* __restrict__ stats_acc,
        const float* __restrict__ resid,
        unsigned short* __restrict__ y_bf,
        float* __restrict__ y_f32,
        const unsigned short* __restrict__ zbuf) {
    constexpr int NCC = CIN / 32;          // K-chunks of 32 channels
    constexpr int NT  = 3 * NCC;           // total chunks (kh major)
    // A: [130 rows][32 ch] bf16 = 8320 B/buf; rows 0,129 are zero edge-halo.
    __shared__ unsigned short Ash[2][130 * 32];

    const int tid = threadIdx.x;
    const int h = blockIdx.x, b = blockIdx.y;
    const int cobase = blockIdx.z * 128;
    const int lane = tid & 63, wave = tid >> 6;
    const int wn = (wave & 1) * 64, wd = (wave >> 1) * 64;
    const int l15 = lane & 15, quad = lane >> 4;

    f32x4 acc[4][4];
    #pragma unroll
    for (int i = 0; i < 4; ++i)
        #pragma unroll
        for (int j = 0; j < 4; ++j)
            acc[i][j] = (f32x4){0.f, 0.f, 0.f, 0.f};

    // per-lane W base (ushort units): cout row (cobase+wd+l15), chan sub quad*8
    const unsigned short* wlane = wt + (size_t)(cobase + wd + l15) * CIN + quad * 8;

    auto stageA = [&](int buf, int t) {
        const int kh = t / NCC, cc = t - kh * NCC;
        const int r = h + kh - 1;
        const bool oob = ((unsigned)r >= (unsigned)HH);
        const char* abase = oob ? (const char*)zbuf
            : (const char*)(xt + ((size_t)(b * HW + r * WW)) * CIN + cc * 32);
        // A rows 1..128 (pos 0..127): 8192 B = 2 issues/thread
        #pragma unroll
        for (int j = 0; j < 2; ++j) {
            const int ob = 64 + (tid + j * 256) * 16;   // linear dest byte
            const int row = ob >> 6, cb = ob & 63;
            const int sel = (row >> 1) & 3;
            const char* src = oob ? abase + cb
                : abase + (size_t)(row - 1) * (CIN * 2) + (cb ^ (sel << 4));
            gload_lds16(src, (char*)Ash[buf] + 64 + (wave * 64 + j * 256) * 16);
        }
    };

    // zero the W-edge halo rows (0 and 129) of both A buffers, once.
    if (tid < 16) {
        int buf = tid >> 3, hi = (tid >> 2) & 1, q = tid & 3;
        *(f32x4*)((char*)Ash[buf] + (hi ? 129 * 64 : 0) + q * 16) =
            (f32x4){0.f, 0.f, 0.f, 0.f};
    }
    stageA(0, 0);
    __syncthreads();

    int curb = 0;
    for (int t = 0; t < NT; ++t) {
        const int kh = t / NCC, cc = t - kh * NCC;
        // W fragments for this chunk: 12 x 16B register loads (no LDS).
        bf16x8 wreg[3][4];
        #pragma unroll
        for (int kw = 0; kw < 3; ++kw)
            #pragma unroll
            for (int fd = 0; fd < 4; ++fd)
                wreg[kw][fd] = *(const bf16x8*)(wlane
                    + (size_t)((kh * 3 + kw) * COUT + fd * 16) * CIN + cc * 32);
        if (t + 1 < NT) stageA(curb ^ 1, t + 1);
        #pragma unroll
        for (int kw = 0; kw < 3; ++kw) {
            bf16x8 a[4];
            #pragma unroll
            for (int fn = 0; fn < 4; ++fn) {
                int ra = wn + fn * 16 + l15 + kw;
                a[fn] = *(const bf16x8*)&Ash[curb][ra * 32 +
                            (quad * 8 ^ (((ra >> 1) & 3) << 3))];
            }
            #pragma unroll
            for (int fn = 0; fn < 4; ++fn)
                #pragma unroll
                for (int fd = 0; fd < 4; ++fd)
                    acc[fn][fd] = __builtin_amdgcn_mfma_f32_16x16x32_bf16(
                        a[fn], wreg[kw][fd], acc[fn][fd], 0, 0, 0);
        }
        __syncthreads();
        curb ^= 1;
    }

    if (CONV1) {
        float gsum[4] = {0.f,0.f,0.f,0.f}, gss[4] = {0.f,0.f,0.f,0.f};
        #pragma unroll
        for (int fd = 0; fd < 4; ++fd) {
            int d = wd + fd * 16 + l15;
            float bv = bias[d];
            #pragma unroll
            for (int fn = 0; fn < 4; ++fn) {
                #pragma unroll
                for (int reg = 0; reg < 4; ++reg) {
                    int n = wn + fn * 16 + quad * 4 + reg;
                    float v = acc[fn][fd][reg] + bv;
                    y_bf[((size_t)(b * HW + h * WW + n)) * 128 + d] = f2bf(v);
                    gsum[fd] += v; gss[fd] += v * v;
                }
            }
        }
        #pragma unroll
        for (int fd = 0; fd < 4; ++fd) {
            float s = gsum[fd], q = gss[fd];
            for (int o = 32; o > 0; o >>= 1) {
                s += __shfl_down(s, o);
                q += __shfl_down(q, o);
            }
            if (lane == 0) {
                int g = (wd >> 4) + fd;
                atomicAdd(&stats_acc[(b * 8 + g) * 2], s);
                atomicAdd(&stats_acc[(b * 8 + g) * 2 + 1], q);
            }
        }
    } else {
        #pragma unroll
        for (int fd = 0; fd < 4; ++fd) {
            int co = cobase + wd + fd * 16 + l15;
            float bv = bias[co];
            #pragma unroll
            for (int fn = 0; fn < 4; ++fn) {
                int n0 = wn + fn * 16 + quad * 4;
                size_t ofs = ((size_t)(b * 256 + co)) * HW + h * WW + n0;
                float4 rs = *(const float4*)(resid + ofs);
                float4 o;
                o.x = acc[fn][fd][0] + bv + rs.x;
                o.y = acc[fn][fd][1] + bv + rs.y;
                o.z = acc[fn][fd][2] + bv + rs.z;
                o.w = acc[fn][fd][3] + bv + rs.w;
                *(float4*)(y_f32 + ofs) = o;
            }
        }
    }
}

// ---------------------------------------------------------------------------
__global__ void gn_finalize(float* stats) {   // [64][2] sums -> mean,rstd
    int t = threadIdx.x;
    if (t < 64) {
        float s = stats[t*2], q = stats[t*2+1];
        const float inv = 1.0f / 262144.0f;   // 16 ch * HW
        float mean = s * inv;
        float var = q * inv - mean * mean;
        stats[t*2] = mean;
        stats[t*2+1] = rsqrtf(var + 1e-5f);
    }
}

// ---------------------------------------------------------------------------
// GN apply + exact GELU (unchanged)
// ---------------------------------------------------------------------------
__global__ __launch_bounds__(256) void gn_gelu(
        unsigned short* __restrict__ y, const float* __restrict__ stats,
        const float* __restrict__ scale, const float* __restrict__ bias) {
    size_t i = (size_t)blockIdx.x * 256 + threadIdx.x;  // ushort4 index
    size_t e = i * 4;
    int d = (int)(e & 127);
    int b = (int)(e >> 21);
    int g = b * 8 + (d >> 4);
    float mean = stats[g * 2], rstd = stats[g * 2 + 1];
    ushort4 v = *(ushort4*)&y[e];
    unsigned short vs[4] = {v.x, v.y, v.z, v.w};
    #pragma unroll
    for (int j = 0; j < 4; ++j) {
        float a = rstd * scale[d + j];
        float c = bias[d + j] - mean * a;
        float t = bf2f(vs[j]) * a + c;
        vs[j] = f2bf(0.5f * t * (1.0f + erff(t * 0.70710678118654752f)));
    }
    ushort4 o = {vs[0], vs[1], vs[2], vs[3]};
    *(ushort4*)&y[e] = o;
}

// ---------------------------------------------------------------------------
// GRU unified GEMM, K=384: X in LDS (2-phase gload_lds), W in registers.
// ---------------------------------------------------------------------------
__global__ __launch_bounds__(256, 4) void gru_gemm(
        const unsigned short* __restrict__ sp_t,
        const unsigned short* __restrict__ ph_t,
        const unsigned short* __restrict__ wg,
        unsigned short* __restrict__ G) {
    __shared__ unsigned short Xs[2][128 * 32];
    const int tid = threadIdx.x;
    const int nt = blockIdx.x, mt = blockIdx.y;
    const size_t p0 = (size_t)nt * 128;
    const int lane = tid & 63, wave = tid >> 6;
    const int wn = (wave & 1) * 64, wm = (wave >> 1) * 64;
    const int l15 = lane & 15, quad = lane >> 4;

    f32x4 acc[4][4];
    #pragma unroll
    for (int i = 0; i < 4; ++i)
        #pragma unroll
        for (int j = 0; j < 4; ++j)
            acc[i][j] = (f32x4){0.f, 0.f, 0.f, 0.f};

    const unsigned short* wlane = wg + (size_t)(mt * 128 + wm + l15) * 384 + quad * 8;

    auto stageX = [&](int buf, int ck) {
        const int k0 = ck * 32;
        const char* xb = (const char*)((k0 < 128)
            ? sp_t + p0 * 128 + k0
            : ph_t + p0 * 128 + (k0 & 127));
        #pragma unroll
        for (int j = 0; j < 2; ++j) {
            const int ob = (tid + j * 256) * 16;
            const int row = ob >> 6, cb = ob & 63;
            const int sel = (row >> 1) & 3;
            gload_lds16(xb + (size_t)row * 256 + (cb ^ (sel << 4)),
                        (char*)Xs[buf] + (wave * 64 + j * 256) * 16);
        }
    };

    stageX(0, 0);
    __syncthreads();
    int curb = 0;
    for (int ck = 0; ck < 12; ++ck) {
        const int k0 = ck * 32;
        bf16x8 wreg[4];
        #pragma unroll
        for (int fm = 0; fm < 4; ++fm)
            wreg[fm] = *(const bf16x8*)(wlane + (size_t)(fm * 16) * 384 + k0);
        if (ck + 1 < 12) stageX(curb ^ 1, ck + 1);
        bf16x8 a[4];
        #pragma unroll
        for (int fn = 0; fn < 4; ++fn) {
            int row = wn + fn * 16 + l15;
            a[fn] = *(const bf16x8*)&Xs[curb][row * 32 +
                        (quad * 8 ^ (((row >> 1) & 3) << 3))];
        }
        #pragma unroll
        for (int fn = 0; fn < 4; ++fn)
            #pragma unroll
            for (int fm = 0; fm < 4; ++fm)
                acc[fn][fm] = __builtin_amdgcn_mfma_f32_16x16x32_bf16(
                    a[fn], wreg[fm], acc[fn][fm], 0, 0, 0);
        __syncthreads();
        curb ^= 1;
    }
    #pragma unroll
    for (int fm = 0; fm < 4; ++fm) {
        int m = mt * 128 + wm + fm * 16 + l15;
        #pragma unroll
        for (int fn = 0; fn < 4; ++fn)
            #pragma unroll
            for (int reg = 0; reg < 4; ++reg) {
                int n = wn + fn * 16 + quad * 4 + reg;
                G[(p0 + n) * 512 + m] = f2bf(acc[fn][fm][reg]);
            }
    }
}

// ---------------------------------------------------------------------------
// GRU gates + h_new (unchanged)
// ---------------------------------------------------------------------------
__global__ __launch_bounds__(256) void gru_gate(
        const unsigned short* __restrict__ G,
        const float* __restrict__ ce_g,
        const float* __restrict__ b_ih, const float* __restrict__ b_hh,
        const float* __restrict__ prev_f32,
        float* __restrict__ new_hidden, unsigned short* __restrict__ hn_t) {
    __shared__ float T[128][65];
    const int tid = threadIdx.x;
    const size_t p0 = (size_t)blockIdx.x * 64;
    const int b = (int)(p0 >> 14);
    const int hw0 = (int)(p0 & (HW - 1));
    const int d = tid & 127;
    const float br  = b_ih[d]       + b_hh[d];
    const float bz  = b_ih[128 + d] + b_hh[128 + d];
    const float bin = b_ih[256 + d];
    const float bhn = b_hh[256 + d];
    for (int j = 0; j < 32; ++j) {
        int pp = (tid >> 7) + j * 2;
        size_t gbase = (p0 + pp) * 512;
        size_t cbase = (size_t)(hw0 + pp) * 384;
        float rl = bf2f(G[gbase + d])       + ce_g[cbase + d]       + br;
        float zl = bf2f(G[gbase + 128 + d]) + ce_g[cbase + 128 + d] + bz;
        float il = bf2f(G[gbase + 256 + d]) + ce_g[cbase + 256 + d] + bin;
        float hl = bf2f(G[gbase + 384 + d]) + bhn;
        float r = 1.0f / (1.0f + expf(-rl));
        float z = 1.0f / (1.0f + expf(-zl));
        float n = tanhf(il + r * hl);
        float hp = prev_f32[((size_t)(b * 128 + d)) * HW + hw0 + pp];
        float hn = (1.0f - z) * n + z * hp;
        T[d][pp] = hn;
        hn_t[(p0 + pp) * 128 + d] = f2bf(hn);
    }
    __syncthreads();
    #pragma unroll
    for (int j = 0; j < 8; ++j) {
        int idx = tid + j * 256;
        int d2 = idx >> 4, pp4 = (idx & 15) * 4;
        float4 v = { T[d2][pp4], T[d2][pp4+1], T[d2][pp4+2], T[d2][pp4+3] };
        *(float4*)&new_hidden[((size_t)(b * 128 + d2)) * HW + hw0 + pp4] = v;
    }
}

// ---------------------------------------------------------------------------
extern "C" void kernel_launch(void* const* d_in, const int* in_sizes, int n_in,
                              void* d_out, int out_size, void* d_ws, size_t ws_size,
                              hipStream_t stream) {
    const float* current_feat = (const float*)d_in[0];
    const float* prev_hidden  = (const float*)d_in[1];
    const float* conv1_w = (const float*)d_in[2];
    const float* conv1_b = (const float*)d_in[3];
    const float* gn_scale = (const float*)d_in[4];
    const float* gn_bias  = (const float*)d_in[5];
    const float* ce_w1 = (const float*)d_in[6];
    const float* ce_b1 = (const float*)d_in[7];
    const float* ce_w2 = (const float*)d_in[8];
    const float* ce_b2 = (const float*)d_in[9];
    const float* w_ih = (const float*)d_in[10];
    const float* b_ih = (const float*)d_in[11];
    const float* w_hh = (const float*)d_in[12];
    const float* b_hh = (const float*)d_in[13];
    const float* conv2_w = (const float*)d_in[14];
    const float* conv2_b = (const float*)d_in[15];

    char* ws = (char*)d_ws;
    unsigned short* cf_t = (unsigned short*)(ws);               // [0, 64Mi)
    unsigned short* ph_t = (unsigned short*)(ws + 67108864);    // [64Mi, 96Mi)
    unsigned short* sp_t = (unsigned short*)(ws + 100663296);   // [96Mi, 128Mi)
    unsigned short* w1t  = (unsigned short*)(ws + 134217728);
    unsigned short* w2t  = (unsigned short*)(ws + 134807552);
    unsigned short* wg   = (unsigned short*)(ws + 135397376);
    float* Mmat          = (float*)(ws + 135790592);            // 64x384 fp32
    float* cebias        = (float*)(ws + 135888896);            // 384 fp32
    float* stats         = (float*)(ws + 135890432);            // 128 fp32
    unsigned short* zbuf = (unsigned short*)(ws + 135890944);   // 256B zeros
    unsigned short* hn_t = cf_t;                                // reuse [0,32Mi)
    float* ce_g          = (float*)(ws + 33554432);             // reuse [32Mi,~56Mi)
    unsigned short* G    = (unsigned short*)d_out;              // 128 MiB scratch
    float* out_feat      = (float*)d_out;
    float* new_hidden    = (float*)d_out + 33554432;

    hipMemsetAsync(stats, 0, 512, stream);
    hipMemsetAsync(zbuf, 0, 256, stream);
    hipLaunchKernelGGL(repack_weights, dim3(1152), dim3(256), 0, stream,
                       conv1_w, conv2_w, w_ih, w_hh, w1t, w2t, wg);
    hipLaunchKernelGGL(prep_ce, dim3(98), dim3(256), 0, stream,
                       ce_w2, ce_b2, w_ih, Mmat, cebias);
    hipLaunchKernelGGL(transpose_cast, dim3(256, 8, 8), dim3(256), 0, stream,
                       current_feat, cf_t, 256);
    hipLaunchKernelGGL(transpose_cast, dim3(256, 4, 8), dim3(256), 0, stream,
                       prev_hidden, ph_t, 128);
    hipLaunchKernelGGL((conv_mfma<256, 128, true>), dim3(128, 8, 1), dim3(256), 0, stream,
                       cf_t, w1t, conv1_b, stats, nullptr, sp_t, nullptr, zbuf);
    hipLaunchKernelGGL(ce_g_kernel, dim3(1024), dim3(384), 0, stream,
                       ce_w1, ce_b1, Mmat, cebias, ce_g);   // after conv1 (reuses cf_t space)
    hipLaunchKernelGGL(gn_finalize, dim3(1), dim3(64), 0, stream, stats);
    hipLaunchKernelGGL(gn_gelu, dim3(16384), dim3(256), 0, stream,
                       sp_t, stats, gn_scale, gn_bias);
    hipLaunchKernelGGL(gru_gemm, dim3(1024, 4), dim3(256), 0, stream,
                       sp_t, ph_t, wg, G);
    hipLaunchKernelGGL(gru_gate, dim3(2048), dim3(256), 0, stream,
                       G, ce_g, b_ih, b_hh, prev_hidden, new_hidden, hn_t);
    hipLaunchKernelGGL((conv_mfma<128, 256, false>), dim3(128, 8, 2), dim3(256), 0, stream,
                       hn_t, w2t, conv2_b, nullptr, current_feat, nullptr, out_feat, zbuf);
}

// Round 3
// 1008.462 us; speedup vs baseline: 1.2089x; 1.2089x over previous
//
#include <hip/hip_runtime.h>
#include <math.h>

#define BH 8
#define HH 128
#define WW 128
#define HW 16384

typedef __attribute__((ext_vector_type(8))) short bf16x8;
typedef __attribute__((ext_vector_type(4))) float f32x4;

__device__ inline unsigned short f2bf(float f) {
    union { float f; unsigned u; } v; v.f = f;
    unsigned r = v.u + 0x7FFF + ((v.u >> 16) & 1);
    return (unsigned short)(r >> 16);
}
__device__ inline float bf2f(unsigned short u) {
    union { unsigned u; float f; } v; v.u = (unsigned)u << 16;
    return v.f;
}

// async global->LDS, 16B per lane. LDS dest must be wave-uniform base (+lane*16).
typedef const __attribute__((address_space(1))) void* gptr_t;
typedef __attribute__((address_space(3))) void* lptr_t;
__device__ inline void gload_lds16(const void* g, void* l) {
    __builtin_amdgcn_global_load_lds((gptr_t)g, (lptr_t)l, 16, 0, 0);
}

// ---------------------------------------------------------------------------
// transpose+cast: [B][C][HW] f32 -> chunked [B][C/32][HW][32] bf16
// ---------------------------------------------------------------------------
__global__ __launch_bounds__(256) void transpose_cast(
        const float* __restrict__ in, unsigned short* __restrict__ out, int C) {
    __shared__ float T[32][65];
    int tid = threadIdx.x;
    int pb = blockIdx.x * 64, cb = blockIdx.y * 32, b = blockIdx.z;
    #pragma unroll
    for (int j = 0; j < 8; ++j) {
        int idx = tid + j * 256;
        int c = idx >> 6, p = idx & 63;
        T[c][p] = in[((size_t)(b * C + cb + c)) * HW + pb + p];
    }
    __syncthreads();
    #pragma unroll
    for (int j = 0; j < 8; ++j) {
        int idx = tid + j * 256;
        int p = idx >> 5, c = idx & 31;
        out[((size_t)(b * (C / 32) + blockIdx.y) * HW + pb + p) * 32 + c] = f2bf(T[c][p]);
    }
}

// ---------------------------------------------------------------------------
// weight repack to bf16, MFMA-B-fragment order:
//  w1t: idx = ((((t*8+cc)*8 + f16)*4 + quad)*16 + l15)*8 + e
//       (cout = f16*16+l15, ch = cc*32+quad*8+e), t = kh*3+kw
//  w2t: same with NCC=4, NF16=16
//  wg : idx = (((ck*32 + f16)*4 + quad)*16 + l15)*8 + e
//       (m = f16*16+l15, k = ck*32+quad*8+e), K-map as before.
// ---------------------------------------------------------------------------
__global__ __launch_bounds__(256) void repack_weights(
        const float* __restrict__ w1, const float* __restrict__ w2,
        const float* __restrict__ wih, const float* __restrict__ whh,
        unsigned short* __restrict__ w1t, unsigned short* __restrict__ w2t,
        unsigned short* __restrict__ wg) {
    int i = blockIdx.x * 256 + threadIdx.x;
    if (i < 294912) {   // w1t: NCC=8, NF16=8
        int e = i & 7, l15 = (i >> 3) & 15, quad = (i >> 7) & 3;
        int f16 = (i >> 9) & 7, cc = (i >> 12) & 7, t = i >> 15;
        int d = f16 * 16 + l15, c = cc * 32 + quad * 8 + e;
        w1t[i] = f2bf(w1[((size_t)(d * 256 + c)) * 9 + t]);
    }
    if (i < 294912) {   // w2t: NCC=4, NF16=16
        int e = i & 7, l15 = (i >> 3) & 15, quad = (i >> 7) & 3;
        int f16 = (i >> 9) & 15, cc = (i >> 13) & 3, t = i >> 15;
        int co = f16 * 16 + l15, ci = cc * 32 + quad * 8 + e;
        w2t[i] = f2bf(w2[((size_t)(co * 128 + ci)) * 9 + t]);
    }
    if (i < 196608) {   // wg: 12 k-chunks x 32 f16-blocks
        int e = i & 7, l15 = (i >> 3) & 15, quad = (i >> 7) & 3;
        int f16 = (i >> 9) & 31, ck = i >> 14;
        int m = f16 * 16 + l15, k = ck * 32 + quad * 8 + e;
        float v = 0.0f;
        if (m < 384) {
            if (k < 128)       v = wih[(size_t)m * 384 + k];
            else if (k < 256)  v = wih[(size_t)m * 384 + 256 + (k - 128)];
            else               v = (m < 256) ? whh[(size_t)m * 128 + (k - 256)] : 0.0f;
        } else {
            v = (k >= 256) ? whh[(size_t)(m - 128) * 128 + (k - 256)] : 0.0f;
        }
        wg[i] = f2bf(v);
    }
}

// ---------------------------------------------------------------------------
// prep_ce (unchanged)
// ---------------------------------------------------------------------------
__global__ __launch_bounds__(256) void prep_ce(
        const float* __restrict__ w2, const float* __restrict__ b2,
        const float* __restrict__ wih,
        float* __restrict__ M, float* __restrict__ cebias) {
    int i = blockIdx.x * 256 + threadIdx.x;
    if (i < 24576) {
        int j = i / 384, m = i - j * 384;
        float acc = 0.0f;
        for (int d = 0; d < 128; ++d)
            acc = fmaf(w2[(size_t)d * 64 + j], wih[(size_t)m * 384 + 128 + d], acc);
        M[i] = acc;
    } else if (i < 24960) {
        int m = i - 24576;
        float acc = 0.0f;
        for (int d = 0; d < 128; ++d)
            acc = fmaf(b2[d], wih[(size_t)m * 384 + 128 + d], acc);
        cebias[m] = acc;
    }
}

// ---------------------------------------------------------------------------
// ce_g (unchanged)
// ---------------------------------------------------------------------------
__global__ __launch_bounds__(384) void ce_g_kernel(
        const float* __restrict__ w1, const float* __restrict__ b1,
        const float* __restrict__ M, const float* __restrict__ cebias,
        float* __restrict__ ce_g) {
    __shared__ float h1[16][64];
    int m = threadIdx.x;
    int pos0 = blockIdx.x * 16;
    for (int e = m; e < 1024; e += 384) {
        int p = e >> 6, j = e & 63;
        int pos = pos0 + p;
        int hh = pos >> 7, wp = pos & 127;
        float xc = -1.0f + 2.0f * (float)wp / 127.0f;
        float yc = -1.0f + 2.0f * (float)hh / 127.0f;
        float a = xc * w1[j*4+0] + yc * w1[j*4+1]
                + xc * 128.0f * w1[j*4+2] + yc * 128.0f * w1[j*4+3] + b1[j];
        h1[p][j] = fmaxf(a, 0.0f);
    }
    __syncthreads();
    float acc[16];
    float cb = cebias[m];
    #pragma unroll
    for (int p = 0; p < 16; ++p) acc[p] = cb;
    for (int j = 0; j < 64; ++j) {
        float Mv = M[(size_t)j * 384 + m];
        #pragma unroll
        for (int p = 0; p < 16; ++p)
            acc[p] = fmaf(h1[p][j], Mv, acc[p]);
    }
    #pragma unroll
    for (int p = 0; p < 16; ++p)
        ce_g[(size_t)(pos0 + p) * 384 + m] = acc[p];
}

// ---------------------------------------------------------------------------
// MFMA conv (3x3 SAME) as 9 shifted GEMMs.
// Round-5: all global accesses contiguous. A from chunked [b][cc][HW][32]
// (8KB contiguous per chunk, gload_lds pre-swizzled source); W fragments
// packed contiguous 1KB per (t,cc,f16), loaded base+lane*16. XCD h-band
// relabel for halo L2 locality.
// ---------------------------------------------------------------------------
template<int CIN, int COUT, bool CONV1>
__global__ __launch_bounds__(256, 3) void conv_mfma(
        const unsigned short* __restrict__ xt,
        const unsigned short* __restrict__ wt,
        const float* __restrict__ bias,
        float* __restrict__ stats_acc,
        const float* __restrict__ resid,
        unsigned short* __restrict__ y_bf,
        float* __restrict__ y_f32,
        const unsigned short* __restrict__ zbuf) {
    constexpr int NCC  = CIN / 32;
    constexpr int NT   = 3 * NCC;
    constexpr int NF16 = COUT / 16;
    __shared__ unsigned short Ash[2][130 * 32];

    const int tid = threadIdx.x;
    // XCD-band relabel: gridDim.x=128 (%8==0) so xcd = blockIdx.x%8; give each
    // xcd a contiguous band of 16 h-rows so halo rows share that XCD's L2.
    const int h = ((blockIdx.x & 7) << 4) + (blockIdx.x >> 3);
    const int b = blockIdx.y;
    const int cobase = blockIdx.z * 128;
    const int lane = tid & 63, wave = tid >> 6;
    const int wn = (wave & 1) * 64, wd = (wave >> 1) * 64;
    const int l15 = lane & 15, quad = lane >> 4;

    f32x4 acc[4][4];
    #pragma unroll
    for (int i = 0; i < 4; ++i)
        #pragma unroll
        for (int j = 0; j < 4; ++j)
            acc[i][j] = (f32x4){0.f, 0.f, 0.f, 0.f};

    auto stageA = [&](int buf, int t) {
        const int kh = t / NCC, cc = t - kh * NCC;
        const int r = h + kh - 1;
        const bool oob = ((unsigned)r >= (unsigned)HH);
        const char* abase = oob ? (const char*)zbuf
            : (const char*)(xt + ((size_t)(b * NCC + cc) * HW + r * WW) * 32);
        #pragma unroll
        for (int j = 0; j < 2; ++j) {
            const int ob = 64 + (tid + j * 256) * 16;   // linear dest byte
            const int row = ob >> 6, cb = ob & 63;
            const int sel = (row >> 1) & 3;
            const char* src = oob ? abase + cb
                : abase + (size_t)(row - 1) * 64 + (cb ^ (sel << 4));
            gload_lds16(src, (char*)Ash[buf] + 64 + (wave * 64 + j * 256) * 16);
        }
    };

    // zero halo rows 0 and 129 of both buffers (sel=0 for both -> linear ok;
    // zeros are permutation-invariant anyway).
    if (tid < 16) {
        int buf = tid >> 3, hi = (tid >> 2) & 1, q = tid & 3;
        *(f32x4*)((char*)Ash[buf] + (hi ? 129 * 64 : 0) + q * 16) =
            (f32x4){0.f, 0.f, 0.f, 0.f};
    }
    stageA(0, 0);
    __syncthreads();

    int curb = 0;
    for (int t = 0; t < NT; ++t) {
        const int kh = t / NCC, cc = t - kh * NCC;
        // W fragments: 12 x contiguous 1KB streams (base + lane*16), L2-hot.
        bf16x8 wreg[3][4];
        #pragma unroll
        for (int kw = 0; kw < 3; ++kw)
            #pragma unroll
            for (int fd = 0; fd < 4; ++fd) {
                const int f16 = (cobase >> 4) + (wd >> 4) + fd;
                wreg[kw][fd] = *(const bf16x8*)(wt +
                    (((size_t)(kh * 3 + kw) * NCC + cc) * NF16 + f16) * 512 + lane * 8);
            }
        if (t + 1 < NT) stageA(curb ^ 1, t + 1);
        #pragma unroll
        for (int kw = 0; kw < 3; ++kw) {
            bf16x8 a[4];
            #pragma unroll
            for (int fn = 0; fn < 4; ++fn) {
                int ra = wn + fn * 16 + l15 + kw;
                a[fn] = *(const bf16x8*)&Ash[curb][ra * 32 +
                            (quad * 8 ^ (((ra >> 1) & 3) << 3))];
            }
            #pragma unroll
            for (int fn = 0; fn < 4; ++fn)
                #pragma unroll
                for (int fd = 0; fd < 4; ++fd)
                    acc[fn][fd] = __builtin_amdgcn_mfma_f32_16x16x32_bf16(
                        a[fn], wreg[kw][fd], acc[fn][fd], 0, 0, 0);
        }
        __syncthreads();
        curb ^= 1;
    }

    if (CONV1) {
        float gsum[4] = {0.f,0.f,0.f,0.f}, gss[4] = {0.f,0.f,0.f,0.f};
        #pragma unroll
        for (int fd = 0; fd < 4; ++fd) {
            int d = wd + fd * 16 + l15;
            float bv = bias[d];
            #pragma unroll
            for (int fn = 0; fn < 4; ++fn) {
                #pragma unroll
                for (int reg = 0; reg < 4; ++reg) {
                    int n = wn + fn * 16 + quad * 4 + reg;
                    float v = acc[fn][fd][reg] + bv;
                    y_bf[((size_t)(b * 4 + (d >> 5)) * HW + h * WW + n) * 32 + (d & 31)]
                        = f2bf(v);
                    gsum[fd] += v; gss[fd] += v * v;
                }
            }
        }
        #pragma unroll
        for (int fd = 0; fd < 4; ++fd) {
            float s = gsum[fd], q = gss[fd];
            for (int o = 32; o > 0; o >>= 1) {
                s += __shfl_down(s, o);
                q += __shfl_down(q, o);
            }
            if (lane == 0) {
                int g = (wd >> 4) + fd;
                atomicAdd(&stats_acc[(b * 8 + g) * 2], s);
                atomicAdd(&stats_acc[(b * 8 + g) * 2 + 1], q);
            }
        }
    } else {
        #pragma unroll
        for (int fd = 0; fd < 4; ++fd) {
            int co = cobase + wd + fd * 16 + l15;
            float bv = bias[co];
            #pragma unroll
            for (int fn = 0; fn < 4; ++fn) {
                int n0 = wn + fn * 16 + quad * 4;
                size_t ofs = ((size_t)(b * 256 + co)) * HW + h * WW + n0;
                float4 rs = *(const float4*)(resid + ofs);
                float4 o;
                o.x = acc[fn][fd][0] + bv + rs.x;
                o.y = acc[fn][fd][1] + bv + rs.y;
                o.z = acc[fn][fd][2] + bv + rs.z;
                o.w = acc[fn][fd][3] + bv + rs.w;
                *(float4*)(y_f32 + ofs) = o;
            }
        }
    }
}

// ---------------------------------------------------------------------------
__global__ void gn_finalize(float* stats) {   // [64][2] sums -> mean,rstd
    int t = threadIdx.x;
    if (t < 64) {
        float s = stats[t*2], q = stats[t*2+1];
        const float inv = 1.0f / 262144.0f;   // 16 ch * HW
        float mean = s * inv;
        float var = q * inv - mean * mean;
        stats[t*2] = mean;
        stats[t*2+1] = rsqrtf(var + 1e-5f);
    }
}

// ---------------------------------------------------------------------------
// GN apply + exact GELU, in-place on chunked sp_t [b][4][HW][32] bf16
// ---------------------------------------------------------------------------
__global__ __launch_bounds__(256) void gn_gelu(
        unsigned short* __restrict__ y, const float* __restrict__ stats,
        const float* __restrict__ scale, const float* __restrict__ bias) {
    size_t i = (size_t)blockIdx.x * 256 + threadIdx.x;  // ushort4 index
    size_t e = i * 4;
    int c32 = (int)(e & 31);
    int cc = (int)((e >> 19) & 3);
    int b = (int)(e >> 21);
    int d = cc * 32 + c32;
    int g = b * 8 + (d >> 4);
    float mean = stats[g * 2], rstd = stats[g * 2 + 1];
    ushort4 v = *(ushort4*)&y[e];
    unsigned short vs[4] = {v.x, v.y, v.z, v.w};
    #pragma unroll
    for (int j = 0; j < 4; ++j) {
        float a = rstd * scale[d + j];
        float c = bias[d + j] - mean * a;
        float t = bf2f(vs[j]) * a + c;
        vs[j] = f2bf(0.5f * t * (1.0f + erff(t * 0.70710678118654752f)));
    }
    ushort4 o = {vs[0], vs[1], vs[2], vs[3]};
    *(ushort4*)&y[e] = o;
}

// ---------------------------------------------------------------------------
// GRU unified GEMM, K=384: X chunks contiguous 8KB, W frag-packed.
// ---------------------------------------------------------------------------
__global__ __launch_bounds__(256, 4) void gru_gemm(
        const unsigned short* __restrict__ sp_t,
        const unsigned short* __restrict__ ph_t,
        const unsigned short* __restrict__ wg,
        unsigned short* __restrict__ G) {
    __shared__ unsigned short Xs[2][128 * 32];
    const int tid = threadIdx.x;
    const int nt = blockIdx.x, mt = blockIdx.y;
    const size_t p0 = (size_t)nt * 128;
    const int b4 = (nt >> 7) * 4;           // batch * 4 chunks
    const int hw0 = (int)(p0 & (HW - 1));
    const int lane = tid & 63, wave = tid >> 6;
    const int wn = (wave & 1) * 64, wm = (wave >> 1) * 64;
    const int l15 = lane & 15, quad = lane >> 4;

    f32x4 acc[4][4];
    #pragma unroll
    for (int i = 0; i < 4; ++i)
        #pragma unroll
        for (int j = 0; j < 4; ++j)
            acc[i][j] = (f32x4){0.f, 0.f, 0.f, 0.f};

    auto stageX = [&](int buf, int ck) {
        const int cc = ck & 3;   // ck 0-3 -> sp cc; 4-7 -> ph cc; 8-11 -> ph cc
        const unsigned short* srcbuf = (ck < 4) ? sp_t : ph_t;
        const char* xb = (const char*)(srcbuf + ((size_t)(b4 + cc) * HW + hw0) * 32);
        #pragma unroll
        for (int j = 0; j < 2; ++j) {
            const int ob = (tid + j * 256) * 16;
            const int row = ob >> 6, cb = ob & 63;
            const int sel = (row >> 1) & 3;
            gload_lds16(xb + (size_t)row * 64 + (cb ^ (sel << 4)),
                        (char*)Xs[buf] + (wave * 64 + j * 256) * 16);
        }
    };

    stageX(0, 0);
    __syncthreads();
    int curb = 0;
    for (int ck = 0; ck < 12; ++ck) {
        bf16x8 wreg[4];
        #pragma unroll
        for (int fm = 0; fm < 4; ++fm) {
            const int f16 = mt * 8 + (wm >> 4) + fm;
            wreg[fm] = *(const bf16x8*)(wg + ((size_t)(ck * 32 + f16)) * 512 + lane * 8);
        }
        if (ck + 1 < 12) stageX(curb ^ 1, ck + 1);
        bf16x8 a[4];
        #pragma unroll
        for (int fn = 0; fn < 4; ++fn) {
            int row = wn + fn * 16 + l15;
            a[fn] = *(const bf16x8*)&Xs[curb][row * 32 +
                        (quad * 8 ^ (((row >> 1) & 3) << 3))];
        }
        #pragma unroll
        for (int fn = 0; fn < 4; ++fn)
            #pragma unroll
            for (int fm = 0; fm < 4; ++fm)
                acc[fn][fm] = __builtin_amdgcn_mfma_f32_16x16x32_bf16(
                    a[fn], wreg[fm], acc[fn][fm], 0, 0, 0);
        __syncthreads();
        curb ^= 1;
    }
    #pragma unroll
    for (int fm = 0; fm < 4; ++fm) {
        int m = mt * 128 + wm + fm * 16 + l15;
        #pragma unroll
        for (int fn = 0; fn < 4; ++fn)
            #pragma unroll
            for (int reg = 0; reg < 4; ++reg) {
                int n = wn + fn * 16 + quad * 4 + reg;
                G[(p0 + n) * 512 + m] = f2bf(acc[fn][fm][reg]);
            }
    }
}

// ---------------------------------------------------------------------------
// GRU gates + h_new; hn_t written chunked [b][4][HW][32].
// ---------------------------------------------------------------------------
__global__ __launch_bounds__(256) void gru_gate(
        const unsigned short* __restrict__ G,
        const float* __restrict__ ce_g,
        const float* __restrict__ b_ih, const float* __restrict__ b_hh,
        const float* __restrict__ prev_f32,
        float* __restrict__ new_hidden, unsigned short* __restrict__ hn_t) {
    __shared__ float T[128][65];
    const int tid = threadIdx.x;
    const size_t p0 = (size_t)blockIdx.x * 64;
    const int b = (int)(p0 >> 14);
    const int hw0 = (int)(p0 & (HW - 1));
    const int d = tid & 127;
    const float br  = b_ih[d]       + b_hh[d];
    const float bz  = b_ih[128 + d] + b_hh[128 + d];
    const float bin = b_ih[256 + d];
    const float bhn = b_hh[256 + d];
    for (int j = 0; j < 32; ++j) {
        int pp = (tid >> 7) + j * 2;
        size_t gbase = (p0 + pp) * 512;
        size_t cbase = (size_t)(hw0 + pp) * 384;
        float rl = bf2f(G[gbase + d])       + ce_g[cbase + d]       + br;
        float zl = bf2f(G[gbase + 128 + d]) + ce_g[cbase + 128 + d] + bz;
        float il = bf2f(G[gbase + 256 + d]) + ce_g[cbase + 256 + d] + bin;
        float hl = bf2f(G[gbase + 384 + d]) + bhn;
        float r = 1.0f / (1.0f + expf(-rl));
        float z = 1.0f / (1.0f + expf(-zl));
        float n = tanhf(il + r * hl);
        float hp = prev_f32[((size_t)(b * 128 + d)) * HW + hw0 + pp];
        float hn = (1.0f - z) * n + z * hp;
        T[d][pp] = hn;
        hn_t[((size_t)(b * 4 + (d >> 5)) * HW + hw0 + pp) * 32 + (d & 31)] = f2bf(hn);
    }
    __syncthreads();
    #pragma unroll
    for (int j = 0; j < 8; ++j) {
        int idx = tid + j * 256;
        int d2 = idx >> 4, pp4 = (idx & 15) * 4;
        float4 v = { T[d2][pp4], T[d2][pp4+1], T[d2][pp4+2], T[d2][pp4+3] };
        *(float4*)&new_hidden[((size_t)(b * 128 + d2)) * HW + hw0 + pp4] = v;
    }
}

// ---------------------------------------------------------------------------
extern "C" void kernel_launch(void* const* d_in, const int* in_sizes, int n_in,
                              void* d_out, int out_size, void* d_ws, size_t ws_size,
                              hipStream_t stream) {
    const float* current_feat = (const float*)d_in[0];
    const float* prev_hidden  = (const float*)d_in[1];
    const float* conv1_w = (const float*)d_in[2];
    const float* conv1_b = (const float*)d_in[3];
    const float* gn_scale = (const float*)d_in[4];
    const float* gn_bias  = (const float*)d_in[5];
    const float* ce_w1 = (const float*)d_in[6];
    const float* ce_b1 = (const float*)d_in[7];
    const float* ce_w2 = (const float*)d_in[8];
    const float* ce_b2 = (const float*)d_in[9];
    const float* w_ih = (const float*)d_in[10];
    const float* b_ih = (const float*)d_in[11];
    const float* w_hh = (const float*)d_in[12];
    const float* b_hh = (const float*)d_in[13];
    const float* conv2_w = (const float*)d_in[14];
    const float* conv2_b = (const float*)d_in[15];

    char* ws = (char*)d_ws;
    unsigned short* cf_t = (unsigned short*)(ws);               // [0, 64Mi)
    unsigned short* ph_t = (unsigned short*)(ws + 67108864);    // [64Mi, 96Mi)
    unsigned short* sp_t = (unsigned short*)(ws + 100663296);   // [96Mi, 128Mi)
    unsigned short* w1t  = (unsigned short*)(ws + 134217728);
    unsigned short* w2t  = (unsigned short*)(ws + 134807552);
    unsigned short* wg   = (unsigned short*)(ws + 135397376);
    float* Mmat          = (float*)(ws + 135790592);            // 64x384 fp32
    float* cebias        = (float*)(ws + 135888896);            // 384 fp32
    float* stats         = (float*)(ws + 135890432);            // 128 fp32
    unsigned short* zbuf = (unsigned short*)(ws + 135890944);   // 256B zeros
    unsigned short* hn_t = cf_t;                                // reuse [0,32Mi)
    float* ce_g          = (float*)(ws + 33554432);             // reuse [32Mi,~56Mi)
    unsigned short* G    = (unsigned short*)d_out;              // 128 MiB scratch
    float* out_feat      = (float*)d_out;
    float* new_hidden    = (float*)d_out + 33554432;

    hipMemsetAsync(stats, 0, 512, stream);
    hipMemsetAsync(zbuf, 0, 256, stream);
    hipLaunchKernelGGL(repack_weights, dim3(1152), dim3(256), 0, stream,
                       conv1_w, conv2_w, w_ih, w_hh, w1t, w2t, wg);
    hipLaunchKernelGGL(prep_ce, dim3(98), dim3(256), 0, stream,
                       ce_w2, ce_b2, w_ih, Mmat, cebias);
    hipLaunchKernelGGL(transpose_cast, dim3(256, 8, 8), dim3(256), 0, stream,
                       current_feat, cf_t, 256);
    hipLaunchKernelGGL(transpose_cast, dim3(256, 4, 8), dim3(256), 0, stream,
                       prev_hidden, ph_t, 128);
    hipLaunchKernelGGL((conv_mfma<256, 128, true>), dim3(128, 8, 1), dim3(256), 0, stream,
                       cf_t, w1t, conv1_b, stats, nullptr, sp_t, nullptr, zbuf);
    hipLaunchKernelGGL(ce_g_kernel, dim3(1024), dim3(384), 0, stream,
                       ce_w1, ce_b1, Mmat, cebias, ce_g);   // after conv1 (reuses cf_t space)
    hipLaunchKernelGGL(gn_finalize, dim3(1), dim3(64), 0, stream, stats);
    hipLaunchKernelGGL(gn_gelu, dim3(16384), dim3(256), 0, stream,
                       sp_t, stats, gn_scale, gn_bias);
    hipLaunchKernelGGL(gru_gemm, dim3(1024, 4), dim3(256), 0, stream,
                       sp_t, ph_t, wg, G);
    hipLaunchKernelGGL(gru_gate, dim3(2048), dim3(256), 0, stream,
                       G, ce_g, b_ih, b_hh, prev_hidden, new_hidden, hn_t);
    hipLaunchKernelGGL((conv_mfma<128, 256, false>), dim3(128, 8, 2), dim3(256), 0, stream,
                       hn_t, w2t, conv2_b, nullptr, current_feat, nullptr, out_feat, zbuf);
}

// Round 4
// 907.641 us; speedup vs baseline: 1.3431x; 1.1111x over previous
//
#include <hip/hip_runtime.h>
#include <math.h>

#define BH 8
#define HH 128
#define WW 128
#define HW 16384

typedef __attribute__((ext_vector_type(8))) short bf16x8;
typedef __attribute__((ext_vector_type(4))) float f32x4;

__device__ inline unsigned short f2bf(float f) {
    union { float f; unsigned u; } v; v.f = f;
    unsigned r = v.u + 0x7FFF + ((v.u >> 16) & 1);
    return (unsigned short)(r >> 16);
}
__device__ inline float bf2f(unsigned short u) {
    union { unsigned u; float f; } v; v.u = (unsigned)u << 16;
    return v.f;
}

// async global->LDS, 16B per lane. LDS dest must be wave-uniform base (+lane*16).
typedef const __attribute__((address_space(1))) void* gptr_t;
typedef __attribute__((address_space(3))) void* lptr_t;
__device__ inline void gload_lds16(const void* g, void* l) {
    __builtin_amdgcn_global_load_lds((gptr_t)g, (lptr_t)l, 16, 0, 0);
}

// ---------------------------------------------------------------------------
// transpose+cast: [B][C][HW] f32 -> chunked [B][C/32][HW][32] bf16
// ---------------------------------------------------------------------------
__global__ __launch_bounds__(256) void transpose_cast(
        const float* __restrict__ in, unsigned short* __restrict__ out, int C) {
    __shared__ float T[32][65];
    int tid = threadIdx.x;
    int pb = blockIdx.x * 64, cb = blockIdx.y * 32, b = blockIdx.z;
    #pragma unroll
    for (int j = 0; j < 8; ++j) {
        int idx = tid + j * 256;
        int c = idx >> 6, p = idx & 63;
        T[c][p] = in[((size_t)(b * C + cb + c)) * HW + pb + p];
    }
    __syncthreads();
    #pragma unroll
    for (int j = 0; j < 8; ++j) {
        int idx = tid + j * 256;
        int p = idx >> 5, c = idx & 31;
        out[((size_t)(b * (C / 32) + blockIdx.y) * HW + pb + p) * 32 + c] = f2bf(T[c][p]);
    }
}

// ---------------------------------------------------------------------------
// weight repack to bf16, MFMA-B-fragment order (unchanged from round 3)
// ---------------------------------------------------------------------------
__global__ __launch_bounds__(256) void repack_weights(
        const float* __restrict__ w1, const float* __restrict__ w2,
        const float* __restrict__ wih, const float* __restrict__ whh,
        unsigned short* __restrict__ w1t, unsigned short* __restrict__ w2t,
        unsigned short* __restrict__ wg) {
    int i = blockIdx.x * 256 + threadIdx.x;
    if (i < 294912) {   // w1t: NCC=8, NF16=8
        int e = i & 7, l15 = (i >> 3) & 15, quad = (i >> 7) & 3;
        int f16 = (i >> 9) & 7, cc = (i >> 12) & 7, t = i >> 15;
        int d = f16 * 16 + l15, c = cc * 32 + quad * 8 + e;
        w1t[i] = f2bf(w1[((size_t)(d * 256 + c)) * 9 + t]);
    }
    if (i < 294912) {   // w2t: NCC=4, NF16=16
        int e = i & 7, l15 = (i >> 3) & 15, quad = (i >> 7) & 3;
        int f16 = (i >> 9) & 15, cc = (i >> 13) & 3, t = i >> 15;
        int co = f16 * 16 + l15, ci = cc * 32 + quad * 8 + e;
        w2t[i] = f2bf(w2[((size_t)(co * 128 + ci)) * 9 + t]);
    }
    if (i < 196608) {   // wg: 12 k-chunks x 32 f16-blocks
        int e = i & 7, l15 = (i >> 3) & 15, quad = (i >> 7) & 3;
        int f16 = (i >> 9) & 31, ck = i >> 14;
        int m = f16 * 16 + l15, k = ck * 32 + quad * 8 + e;
        float v = 0.0f;
        if (m < 384) {
            if (k < 128)       v = wih[(size_t)m * 384 + k];
            else if (k < 256)  v = wih[(size_t)m * 384 + 256 + (k - 128)];
            else               v = (m < 256) ? whh[(size_t)m * 128 + (k - 256)] : 0.0f;
        } else {
            v = (k >= 256) ? whh[(size_t)(m - 128) * 128 + (k - 256)] : 0.0f;
        }
        wg[i] = f2bf(v);
    }
}

// ---------------------------------------------------------------------------
// prep_ce (unchanged)
// ---------------------------------------------------------------------------
__global__ __launch_bounds__(256) void prep_ce(
        const float* __restrict__ w2, const float* __restrict__ b2,
        const float* __restrict__ wih,
        float* __restrict__ M, float* __restrict__ cebias) {
    int i = blockIdx.x * 256 + threadIdx.x;
    if (i < 24576) {
        int j = i / 384, m = i - j * 384;
        float acc = 0.0f;
        for (int d = 0; d < 128; ++d)
            acc = fmaf(w2[(size_t)d * 64 + j], wih[(size_t)m * 384 + 128 + d], acc);
        M[i] = acc;
    } else if (i < 24960) {
        int m = i - 24576;
        float acc = 0.0f;
        for (int d = 0; d < 128; ++d)
            acc = fmaf(b2[d], wih[(size_t)m * 384 + 128 + d], acc);
        cebias[m] = acc;
    }
}

// ---------------------------------------------------------------------------
// ce_g (unchanged)
// ---------------------------------------------------------------------------
__global__ __launch_bounds__(384) void ce_g_kernel(
        const float* __restrict__ w1, const float* __restrict__ b1,
        const float* __restrict__ M, const float* __restrict__ cebias,
        float* __restrict__ ce_g) {
    __shared__ float h1[16][64];
    int m = threadIdx.x;
    int pos0 = blockIdx.x * 16;
    for (int e = m; e < 1024; e += 384) {
        int p = e >> 6, j = e & 63;
        int pos = pos0 + p;
        int hh = pos >> 7, wp = pos & 127;
        float xc = -1.0f + 2.0f * (float)wp / 127.0f;
        float yc = -1.0f + 2.0f * (float)hh / 127.0f;
        float a = xc * w1[j*4+0] + yc * w1[j*4+1]
                + xc * 128.0f * w1[j*4+2] + yc * 128.0f * w1[j*4+3] + b1[j];
        h1[p][j] = fmaxf(a, 0.0f);
    }
    __syncthreads();
    float acc[16];
    float cb = cebias[m];
    #pragma unroll
    for (int p = 0; p < 16; ++p) acc[p] = cb;
    for (int j = 0; j < 64; ++j) {
        float Mv = M[(size_t)j * 384 + m];
        #pragma unroll
        for (int p = 0; p < 16; ++p)
            acc[p] = fmaf(h1[p][j], Mv, acc[p]);
    }
    #pragma unroll
    for (int p = 0; p < 16; ++p)
        ce_g[(size_t)(pos0 + p) * 384 + m] = acc[p];
}

// ---------------------------------------------------------------------------
// MFMA conv (3x3 SAME), round-6: TWO output rows per block.
// Chunk = (kh, cc32): stages the two input rows {h0+kh-1, h0+kh} (16 KB
// contiguous) into a shared-halo LDS layout [2*129+1][32] (right halo of
// row0 == left halo of row1 == zero). Per chunk: 96 MFMA/wave (2 out-rows
// reuse the same W regs) vs one barrier -> compute phase (~920 cy across
// 2 waves/SIMD) now covers the stage latency (~900 cy). W regs for chunk
// t+1 are loaded BEFORE the barrier (completed by its vmcnt(0) for free).
// ---------------------------------------------------------------------------
template<int CIN, int COUT, bool CONV1>
__global__ __launch_bounds__(256, 2) void conv_mfma(
        const unsigned short* __restrict__ xt,
        const unsigned short* __restrict__ wt,
        const float* __restrict__ bias,
        float* __restrict__ stats_acc,
        const float* __restrict__ resid,
        unsigned short* __restrict__ y_bf,
        float* __restrict__ y_f32,
        const unsigned short* __restrict__ zbuf) {
    constexpr int NCC  = CIN / 32;
    constexpr int NT   = 3 * NCC;
    constexpr int NF16 = COUT / 16;
    // 259 slots x 64B per buffer; slot s = ri*129 + 1 + pos; slots 0,129,258
    // are the shared zero halos. 16576 B/buf, 33152 B total.
    __shared__ unsigned short Ash[2][259 * 32];

    const int tid = threadIdx.x;
    // XCD band relabel over 64 h-pair blocks (8 bands of 8).
    const int hp = ((blockIdx.x & 7) << 3) + (blockIdx.x >> 3);
    const int h0 = hp * 2;
    const int b = blockIdx.y;
    const int cobase = blockIdx.z * 128;
    const int lane = tid & 63, wave = tid >> 6;
    const int wn = (wave & 1) * 64, wd = (wave >> 1) * 64;
    const int l15 = lane & 15, quad = lane >> 4;

    f32x4 acc[2][4][4];
    #pragma unroll
    for (int r = 0; r < 2; ++r)
        #pragma unroll
        for (int i = 0; i < 4; ++i)
            #pragma unroll
            for (int j = 0; j < 4; ++j)
                acc[r][i][j] = (f32x4){0.f, 0.f, 0.f, 0.f};

    auto stageA = [&](int buf, int t) {
        const int kh = t / NCC, cc = t - kh * NCC;
        #pragma unroll
        for (int ri = 0; ri < 2; ++ri) {
            const int r = h0 + kh - 1 + ri;
            const bool oob = ((unsigned)r >= (unsigned)HH);
            const char* abase = oob ? (const char*)zbuf
                : (const char*)(xt + ((size_t)(b * NCC + cc) * HW + r * WW) * 32);
            #pragma unroll
            for (int j = 0; j < 2; ++j) {
                const int ob = 64 + (tid + j * 256) * 16;   // dest byte in ri-block
                const int row = ob >> 6, cb = ob & 63;      // row = 1+pos
                const int sel = (row >> 1) & 3;
                const char* src = oob ? abase + cb
                    : abase + (size_t)(row - 1) * 64 + (cb ^ (sel << 4));
                gload_lds16(src, (char*)Ash[buf] + ri * 8256 + 64 +
                                 (wave * 64 + j * 256) * 16);
            }
        }
    };

    // load W fragments for chunk t into wreg
    bf16x8 wreg[3][4];
    auto loadW = [&](int t) {
        const int kh = t / NCC, cc = t - kh * NCC;
        #pragma unroll
        for (int kw = 0; kw < 3; ++kw)
            #pragma unroll
            for (int fd = 0; fd < 4; ++fd) {
                const int f16 = (cobase >> 4) + (wd >> 4) + fd;
                wreg[kw][fd] = *(const bf16x8*)(wt +
                    (((size_t)(kh * 3 + kw) * NCC + cc) * NF16 + f16) * 512 + lane * 8);
            }
    };

    // zero the shared halo slots (0,129,258)*64B in both buffers
    if (tid < 24) {
        int buf = tid / 12, s = (tid % 12) >> 2, q = tid & 3;
        *(f32x4*)((char*)Ash[buf] + s * 8256 + q * 16) = (f32x4){0.f,0.f,0.f,0.f};
    }
    stageA(0, 0);
    loadW(0);
    __syncthreads();

    int curb = 0;
    for (int t = 0; t < NT; ++t) {
        if (t + 1 < NT) stageA(curb ^ 1, t + 1);
        #pragma unroll
        for (int kw = 0; kw < 3; ++kw) {
            #pragma unroll
            for (int ri = 0; ri < 2; ++ri) {
                bf16x8 a[4];
                #pragma unroll
                for (int fn = 0; fn < 4; ++fn) {
                    int ra = wn + fn * 16 + l15 + kw;       // within-block slot
                    a[fn] = *(const bf16x8*)&Ash[curb][ri * 4128 + ra * 32 +
                                (quad * 8 ^ (((ra >> 1) & 3) << 3))];
                }
                #pragma unroll
                for (int fn = 0; fn < 4; ++fn)
                    #pragma unroll
                    for (int fd = 0; fd < 4; ++fd)
                        acc[ri][fn][fd] = __builtin_amdgcn_mfma_f32_16x16x32_bf16(
                            a[fn], wreg[kw][fd], acc[ri][fn][fd], 0, 0, 0);
            }
        }
        if (t + 1 < NT) loadW(t + 1);   // completes at the barrier's vmcnt(0)
        __syncthreads();
        curb ^= 1;
    }

    if (CONV1) {
        float gsum[4] = {0.f,0.f,0.f,0.f}, gss[4] = {0.f,0.f,0.f,0.f};
        #pragma unroll
        for (int fd = 0; fd < 4; ++fd) {
            int d = wd + fd * 16 + l15;
            float bv = bias[d];
            #pragma unroll
            for (int ri = 0; ri < 2; ++ri) {
                #pragma unroll
                for (int fn = 0; fn < 4; ++fn) {
                    #pragma unroll
                    for (int reg = 0; reg < 4; ++reg) {
                        int n = wn + fn * 16 + quad * 4 + reg;
                        float v = acc[ri][fn][fd][reg] + bv;
                        y_bf[((size_t)(b * 4 + (d >> 5)) * HW + (h0 + ri) * WW + n) * 32
                             + (d & 31)] = f2bf(v);
                        gsum[fd] += v; gss[fd] += v * v;
                    }
                }
            }
        }
        #pragma unroll
        for (int fd = 0; fd < 4; ++fd) {
            float s = gsum[fd], q = gss[fd];
            for (int o = 32; o > 0; o >>= 1) {
                s += __shfl_down(s, o);
                q += __shfl_down(q, o);
            }
            if (lane == 0) {
                int g = (wd >> 4) + fd;
                atomicAdd(&stats_acc[(b * 8 + g) * 2], s);
                atomicAdd(&stats_acc[(b * 8 + g) * 2 + 1], q);
            }
        }
    } else {
        #pragma unroll
        for (int fd = 0; fd < 4; ++fd) {
            int co = cobase + wd + fd * 16 + l15;
            float bv = bias[co];
            #pragma unroll
            for (int ri = 0; ri < 2; ++ri) {
                #pragma unroll
                for (int fn = 0; fn < 4; ++fn) {
                    int n0 = wn + fn * 16 + quad * 4;
                    size_t ofs = ((size_t)(b * 256 + co)) * HW + (h0 + ri) * WW + n0;
                    float4 rs = *(const float4*)(resid + ofs);
                    float4 o;
                    o.x = acc[ri][fn][fd][0] + bv + rs.x;
                    o.y = acc[ri][fn][fd][1] + bv + rs.y;
                    o.z = acc[ri][fn][fd][2] + bv + rs.z;
                    o.w = acc[ri][fn][fd][3] + bv + rs.w;
                    *(float4*)(y_f32 + ofs) = o;
                }
            }
        }
    }
}

// ---------------------------------------------------------------------------
__global__ void gn_finalize(float* stats) {   // [64][2] sums -> mean,rstd
    int t = threadIdx.x;
    if (t < 64) {
        float s = stats[t*2], q = stats[t*2+1];
        const float inv = 1.0f / 262144.0f;   // 16 ch * HW
        float mean = s * inv;
        float var = q * inv - mean * mean;
        stats[t*2] = mean;
        stats[t*2+1] = rsqrtf(var + 1e-5f);
    }
}

// ---------------------------------------------------------------------------
// GN apply + exact GELU, in-place on chunked sp_t [b][4][HW][32] bf16
// ---------------------------------------------------------------------------
__global__ __launch_bounds__(256) void gn_gelu(
        unsigned short* __restrict__ y, const float* __restrict__ stats,
        const float* __restrict__ scale, const float* __restrict__ bias) {
    size_t i = (size_t)blockIdx.x * 256 + threadIdx.x;  // ushort4 index
    size_t e = i * 4;
    int c32 = (int)(e & 31);
    int cc = (int)((e >> 19) & 3);
    int b = (int)(e >> 21);
    int d = cc * 32 + c32;
    int g = b * 8 + (d >> 4);
    float mean = stats[g * 2], rstd = stats[g * 2 + 1];
    ushort4 v = *(ushort4*)&y[e];
    unsigned short vs[4] = {v.x, v.y, v.z, v.w};
    #pragma unroll
    for (int j = 0; j < 4; ++j) {
        float a = rstd * scale[d + j];
        float c = bias[d + j] - mean * a;
        float t = bf2f(vs[j]) * a + c;
        vs[j] = f2bf(0.5f * t * (1.0f + erff(t * 0.70710678118654752f)));
    }
    ushort4 o = {vs[0], vs[1], vs[2], vs[3]};
    *(ushort4*)&y[e] = o;
}

// ---------------------------------------------------------------------------
// GRU unified GEMM, K=384: X chunks contiguous 8KB, W frag-packed.
// (unchanged from round 3)
// ---------------------------------------------------------------------------
__global__ __launch_bounds__(256, 4) void gru_gemm(
        const unsigned short* __restrict__ sp_t,
        const unsigned short* __restrict__ ph_t,
        const unsigned short* __restrict__ wg,
        unsigned short* __restrict__ G) {
    __shared__ unsigned short Xs[2][128 * 32];
    const int tid = threadIdx.x;
    const int nt = blockIdx.x, mt = blockIdx.y;
    const size_t p0 = (size_t)nt * 128;
    const int b4 = (nt >> 7) * 4;           // batch * 4 chunks
    const int hw0 = (int)(p0 & (HW - 1));
    const int lane = tid & 63, wave = tid >> 6;
    const int wn = (wave & 1) * 64, wm = (wave >> 1) * 64;
    const int l15 = lane & 15, quad = lane >> 4;

    f32x4 acc[4][4];
    #pragma unroll
    for (int i = 0; i < 4; ++i)
        #pragma unroll
        for (int j = 0; j < 4; ++j)
            acc[i][j] = (f32x4){0.f, 0.f, 0.f, 0.f};

    auto stageX = [&](int buf, int ck) {
        const int cc = ck & 3;
        const unsigned short* srcbuf = (ck < 4) ? sp_t : ph_t;
        const char* xb = (const char*)(srcbuf + ((size_t)(b4 + cc) * HW + hw0) * 32);
        #pragma unroll
        for (int j = 0; j < 2; ++j) {
            const int ob = (tid + j * 256) * 16;
            const int row = ob >> 6, cb = ob & 63;
            const int sel = (row >> 1) & 3;
            gload_lds16(xb + (size_t)row * 64 + (cb ^ (sel << 4)),
                        (char*)Xs[buf] + (wave * 64 + j * 256) * 16);
        }
    };

    stageX(0, 0);
    __syncthreads();
    int curb = 0;
    for (int ck = 0; ck < 12; ++ck) {
        bf16x8 wreg[4];
        #pragma unroll
        for (int fm = 0; fm < 4; ++fm) {
            const int f16 = mt * 8 + (wm >> 4) + fm;
            wreg[fm] = *(const bf16x8*)(wg + ((size_t)(ck * 32 + f16)) * 512 + lane * 8);
        }
        if (ck + 1 < 12) stageX(curb ^ 1, ck + 1);
        bf16x8 a[4];
        #pragma unroll
        for (int fn = 0; fn < 4; ++fn) {
            int row = wn + fn * 16 + l15;
            a[fn] = *(const bf16x8*)&Xs[curb][row * 32 +
                        (quad * 8 ^ (((row >> 1) & 3) << 3))];
        }
        #pragma unroll
        for (int fn = 0; fn < 4; ++fn)
            #pragma unroll
            for (int fm = 0; fm < 4; ++fm)
                acc[fn][fm] = __builtin_amdgcn_mfma_f32_16x16x32_bf16(
                    a[fn], wreg[fm], acc[fn][fm], 0, 0, 0);
        __syncthreads();
        curb ^= 1;
    }
    #pragma unroll
    for (int fm = 0; fm < 4; ++fm) {
        int m = mt * 128 + wm + fm * 16 + l15;
        #pragma unroll
        for (int fn = 0; fn < 4; ++fn)
            #pragma unroll
            for (int reg = 0; reg < 4; ++reg) {
                int n = wn + fn * 16 + quad * 4 + reg;
                G[(p0 + n) * 512 + m] = f2bf(acc[fn][fm][reg]);
            }
    }
}

// ---------------------------------------------------------------------------
// GRU gates + h_new; hn_t written chunked [b][4][HW][32]. (unchanged)
// ---------------------------------------------------------------------------
__global__ __launch_bounds__(256) void gru_gate(
        const unsigned short* __restrict__ G,
        const float* __restrict__ ce_g,
        const float* __restrict__ b_ih, const float* __restrict__ b_hh,
        const float* __restrict__ prev_f32,
        float* __restrict__ new_hidden, unsigned short* __restrict__ hn_t) {
    __shared__ float T[128][65];
    const int tid = threadIdx.x;
    const size_t p0 = (size_t)blockIdx.x * 64;
    const int b = (int)(p0 >> 14);
    const int hw0 = (int)(p0 & (HW - 1));
    const int d = tid & 127;
    const float br  = b_ih[d]       + b_hh[d];
    const float bz  = b_ih[128 + d] + b_hh[128 + d];
    const float bin = b_ih[256 + d];
    const float bhn = b_hh[256 + d];
    for (int j = 0; j < 32; ++j) {
        int pp = (tid >> 7) + j * 2;
        size_t gbase = (p0 + pp) * 512;
        size_t cbase = (size_t)(hw0 + pp) * 384;
        float rl = bf2f(G[gbase + d])       + ce_g[cbase + d]       + br;
        float zl = bf2f(G[gbase + 128 + d]) + ce_g[cbase + 128 + d] + bz;
        float il = bf2f(G[gbase + 256 + d]) + ce_g[cbase + 256 + d] + bin;
        float hl = bf2f(G[gbase + 384 + d]) + bhn;
        float r = 1.0f / (1.0f + expf(-rl));
        float z = 1.0f / (1.0f + expf(-zl));
        float n = tanhf(il + r * hl);
        float hp = prev_f32[((size_t)(b * 128 + d)) * HW + hw0 + pp];
        float hn = (1.0f - z) * n + z * hp;
        T[d][pp] = hn;
        hn_t[((size_t)(b * 4 + (d >> 5)) * HW + hw0 + pp) * 32 + (d & 31)] = f2bf(hn);
    }
    __syncthreads();
    #pragma unroll
    for (int j = 0; j < 8; ++j) {
        int idx = tid + j * 256;
        int d2 = idx >> 4, pp4 = (idx & 15) * 4;
        float4 v = { T[d2][pp4], T[d2][pp4+1], T[d2][pp4+2], T[d2][pp4+3] };
        *(float4*)&new_hidden[((size_t)(b * 128 + d2)) * HW + hw0 + pp4] = v;
    }
}

// ---------------------------------------------------------------------------
extern "C" void kernel_launch(void* const* d_in, const int* in_sizes, int n_in,
                              void* d_out, int out_size, void* d_ws, size_t ws_size,
                              hipStream_t stream) {
    const float* current_feat = (const float*)d_in[0];
    const float* prev_hidden  = (const float*)d_in[1];
    const float* conv1_w = (const float*)d_in[2];
    const float* conv1_b = (const float*)d_in[3];
    const float* gn_scale = (const float*)d_in[4];
    const float* gn_bias  = (const float*)d_in[5];
    const float* ce_w1 = (const float*)d_in[6];
    const float* ce_b1 = (const float*)d_in[7];
    const float* ce_w2 = (const float*)d_in[8];
    const float* ce_b2 = (const float*)d_in[9];
    const float* w_ih = (const float*)d_in[10];
    const float* b_ih = (const float*)d_in[11];
    const float* w_hh = (const float*)d_in[12];
    const float* b_hh = (const float*)d_in[13];
    const float* conv2_w = (const float*)d_in[14];
    const float* conv2_b = (const float*)d_in[15];

    char* ws = (char*)d_ws;
    unsigned short* cf_t = (unsigned short*)(ws);               // [0, 64Mi)
    unsigned short* ph_t = (unsigned short*)(ws + 67108864);    // [64Mi, 96Mi)
    unsigned short* sp_t = (unsigned short*)(ws + 100663296);   // [96Mi, 128Mi)
    unsigned short* w1t  = (unsigned short*)(ws + 134217728);
    unsigned short* w2t  = (unsigned short*)(ws + 134807552);
    unsigned short* wg   = (unsigned short*)(ws + 135397376);
    float* Mmat          = (float*)(ws + 135790592);            // 64x384 fp32
    float* cebias        = (float*)(ws + 135888896);            // 384 fp32
    float* stats         = (float*)(ws + 135890432);            // 128 fp32
    unsigned short* zbuf = (unsigned short*)(ws + 135890944);   // 256B zeros
    unsigned short* hn_t = cf_t;                                // reuse [0,32Mi)
    float* ce_g          = (float*)(ws + 33554432);             // reuse [32Mi,~56Mi)
    unsigned short* G    = (unsigned short*)d_out;              // 128 MiB scratch
    float* out_feat      = (float*)d_out;
    float* new_hidden    = (float*)d_out + 33554432;

    hipMemsetAsync(stats, 0, 512, stream);
    hipMemsetAsync(zbuf, 0, 256, stream);
    hipLaunchKernelGGL(repack_weights, dim3(1152), dim3(256), 0, stream,
                       conv1_w, conv2_w, w_ih, w_hh, w1t, w2t, wg);
    hipLaunchKernelGGL(prep_ce, dim3(98), dim3(256), 0, stream,
                       ce_w2, ce_b2, w_ih, Mmat, cebias);
    hipLaunchKernelGGL(transpose_cast, dim3(256, 8, 8), dim3(256), 0, stream,
                       current_feat, cf_t, 256);
    hipLaunchKernelGGL(transpose_cast, dim3(256, 4, 8), dim3(256), 0, stream,
                       prev_hidden, ph_t, 128);
    hipLaunchKernelGGL((conv_mfma<256, 128, true>), dim3(64, 8, 1), dim3(256), 0, stream,
                       cf_t, w1t, conv1_b, stats, nullptr, sp_t, nullptr, zbuf);
    hipLaunchKernelGGL(ce_g_kernel, dim3(1024), dim3(384), 0, stream,
                       ce_w1, ce_b1, Mmat, cebias, ce_g);   // after conv1 (reuses cf_t space)
    hipLaunchKernelGGL(gn_finalize, dim3(1), dim3(64), 0, stream, stats);
    hipLaunchKernelGGL(gn_gelu, dim3(16384), dim3(256), 0, stream,
                       sp_t, stats, gn_scale, gn_bias);
    hipLaunchKernelGGL(gru_gemm, dim3(1024, 4), dim3(256), 0, stream,
                       sp_t, ph_t, wg, G);
    hipLaunchKernelGGL(gru_gate, dim3(2048), dim3(256), 0, stream,
                       G, ce_g, b_ih, b_hh, prev_hidden, new_hidden, hn_t);
    hipLaunchKernelGGL((conv_mfma<128, 256, false>), dim3(64, 8, 2), dim3(256), 0, stream,
                       hn_t, w2t, conv2_b, nullptr, current_feat, nullptr, out_feat, zbuf);
}